// Round 6
// baseline (270.555 us; speedup 1.0000x reference)
//
#include <hip/hip_runtime.h>

#define NN 4096
#define DD 64
#define KK 5
#define TS 128
#define KH 32          // k-dims staged per phase (2 phases of 32 = DD)
#define NBINS 1024
#define BINMUL 2.0f    // bin width 0.5 over [0, 512)
#define RMED 8388607u  // (NN*NN - 1) / 2
#define MBUF_CAP 8192u // per-block LDS gather capacity (reuses tiles)

struct Ctrl {
  unsigned wcount;   // window-gathered candidate count (MODE 0)
  unsigned wover;    // 1 if any block overflowed its LDS gather buffer
  unsigned gcount;   // fallback-gathered candidate count (MODE 1)
  unsigned sel_bin;  // selected coarse bin
  unsigned rank;     // rank (0-based) within selected bin (fallback path)
  unsigned ok;       // 1 = window path valid (skip MODE 1)
  unsigned wrank;    // rank within window candidates (window path)
  unsigned spref;    // radix-select prefix (built over 4 rounds)
  unsigned srank;    // remaining rank within prefix
  unsigned use_pow;  // 1 if kernel_scales == [0.5,1,2,4,8]
  float median;
  float c2;          // base*0.5*log2(e) : u = exp2(d*c2), terms = u^{1,2,4,8,16}
  float scales[KK];  // base*kernel_scales[k] (general fallback)
};

__device__ inline float fast_exp2(float x) {
  float r;
  asm("v_exp_f32 %0, %1" : "=v"(r) : "v"(x));
  return r;
}

__device__ inline int swz4(int f) {  // float4-slot XOR swizzle -> float offset
  return (f ^ (f >> 3)) << 2;
}

// ---------------- norms ----------------
__global__ void norms_kernel(const float* __restrict__ x, const float* __restrict__ y,
                             float* __restrict__ xn, float* __restrict__ yn) {
  int r = blockIdx.x * blockDim.x + threadIdx.x;  // 0..8191
  const float* src = (r < NN) ? x : y;
  float* dst = (r < NN) ? xn : yn;
  int row = r & (NN - 1);
  const float4* p = (const float4*)(src + (size_t)row * DD);
  float s = 0.f;
#pragma unroll
  for (int i = 0; i < DD / 4; ++i) {
    float4 v = p[i];
    s = fmaf(v.x, v.x, s);
    s = fmaf(v.y, v.y, s);
    s = fmaf(v.z, v.z, s);
    s = fmaf(v.w, v.w, s);
  }
  dst[row] = s;
}

#define FMA_ROW(i, ax)                         \
  acc[i][0] = fmaf(ax, b0.x, acc[i][0]);       \
  acc[i][1] = fmaf(ax, b0.y, acc[i][1]);       \
  acc[i][2] = fmaf(ax, b0.z, acc[i][2]);       \
  acc[i][3] = fmaf(ax, b0.w, acc[i][3]);       \
  acc[i][4] = fmaf(ax, b1.x, acc[i][4]);       \
  acc[i][5] = fmaf(ax, b1.y, acc[i][5]);       \
  acc[i][6] = fmaf(ax, b1.z, acc[i][6]);       \
  acc[i][7] = fmaf(ax, b1.w, acc[i][7]);

// ---------------- pair-tile kernel ----------------
// MODE 0: histogram xx into NBINS bins + gather window [lobin,hibin) into buf
// MODE 1: fallback gather of ctrl->sel_bin into buf (early-exits if ctrl->ok)
// MODE 2: accumulate kernel sums (z=0: xx, z=1: yy, z=2: zz)
template <int MODE>
__global__ void __launch_bounds__(256)
pair_kernel(const float* __restrict__ x, const float* __restrict__ y,
            const float* __restrict__ xn, const float* __restrict__ yn,
            unsigned* __restrict__ hist, Ctrl* __restrict__ ctrl,
            float* __restrict__ buf, double* __restrict__ S,
            int lobin, int hibin, unsigned cap) {
  if (MODE == 1) {
    if (ctrl->ok) return;  // window path succeeded; nothing to do
  }
  __shared__ __align__(16) float tiles[2 * KH * TS];  // 32KB
  float* As = tiles;
  float* Bs = tiles + KH * TS;

  int t = threadIdx.x;
  int sel = (MODE == 2) ? blockIdx.z : 0;
  const float* A = (sel == 1) ? y : x;
  const float* B = (sel == 0) ? x : y;
  const float* An = (sel == 1) ? yn : xn;
  const float* Bn = (sel == 0) ? xn : yn;

  int rowBase = blockIdx.y * TS;
  int colBase = blockIdx.x * TS;

  int tx = t & 15, ty = t >> 4;
  int r0 = ty * 8, c0 = tx * 8;

  // issue norm loads early (in flight during staging/compute)
  float anr[8], bnr[8];
#pragma unroll
  for (int i = 0; i < 8; ++i) anr[i] = An[rowBase + r0 + i];
#pragma unroll
  for (int j = 0; j < 8; ++j) bnr[j] = Bn[colBase + c0 + j];

  // fragment read pointers (swizzled float4 slots; constant across k)
  const float* a0p = As + swz4(r0 >> 2);
  const float* a1p = As + swz4((r0 >> 2) + 1);
  const float* b0p = Bs + swz4(c0 >> 2);
  const float* b1p = Bs + swz4((c0 >> 2) + 1);

  // staging assignment: threads 0..127 -> A rows, 128..255 -> B rows
  int tile = t >> 7;
  int r = t & 127;
  const float* srow = (tile ? B : A) + (size_t)((tile ? colBase : rowBase) + r) * DD;
  float* dbuf = tile ? Bs : As;
  int woff = swz4(r >> 2) | (r & 3);

  float acc[8][8] = {};
#pragma unroll
  for (int p = 0; p < 2; ++p) {
    float4 v[8];
#pragma unroll
    for (int i = 0; i < 8; ++i) v[i] = *(const float4*)(srow + p * KH + i * 4);
    if (p) __syncthreads();  // wait until everyone finished reading phase p-1
#pragma unroll
    for (int i = 0; i < 8; ++i) {
      int k = i * 4;
      dbuf[(k + 0) * TS + woff] = v[i].x;
      dbuf[(k + 1) * TS + woff] = v[i].y;
      dbuf[(k + 2) * TS + woff] = v[i].z;
      dbuf[(k + 3) * TS + woff] = v[i].w;
    }
    __syncthreads();
#pragma unroll 2
    for (int k = 0; k < KH; ++k) {
      const float4 a0 = *(const float4*)(a0p + k * TS);
      const float4 a1 = *(const float4*)(a1p + k * TS);
      const float4 b0 = *(const float4*)(b0p + k * TS);
      const float4 b1 = *(const float4*)(b1p + k * TS);
      FMA_ROW(0, a0.x) FMA_ROW(1, a0.y) FMA_ROW(2, a0.z) FMA_ROW(3, a0.w)
      FMA_ROW(4, a1.x) FMA_ROW(5, a1.y) FMA_ROW(6, a1.z) FMA_ROW(7, a1.w)
    }
  }

  // d[i][j] in place (identical expression in MODE 0/1 -> identical values)
#pragma unroll
  for (int i = 0; i < 8; ++i)
#pragma unroll
    for (int j = 0; j < 8; ++j) acc[i][j] = (anr[i] + bnr[j]) - 2.0f * acc[i][j];

  if (MODE == 0) {
    __shared__ unsigned h[NBINS];  // 4KB
    __shared__ unsigned bcnt, gbase;
    __syncthreads();  // tile reads done; tiles[] reusable as gather buffer
    for (int i = t; i < NBINS; i += 256) h[i] = 0;
    if (t == 0) bcnt = 0;
    __syncthreads();
    float* mbuf = tiles;  // 8192 floats capacity
#pragma unroll
    for (int i = 0; i < 8; ++i)
#pragma unroll
      for (int j = 0; j < 8; ++j) {
        float d = acc[i][j];
        int b = (int)(d * BINMUL);
        b = min(max(b, 0), NBINS - 1);
        atomicAdd(&h[b], 1u);
        if (b >= lobin && b < hibin) {
          unsigned idx = atomicAdd(&bcnt, 1u);
          if (idx < MBUF_CAP) mbuf[idx] = d;
          else ctrl->wover = 1u;
        }
      }
    __syncthreads();
    for (int i = t; i < NBINS; i += 256)
      if (h[i]) atomicAdd(&hist[i], h[i]);
    unsigned cnt = min(bcnt, MBUF_CAP);
    if (t == 0) gbase = atomicAdd(&ctrl->wcount, cnt);
    __syncthreads();
    for (unsigned i = t; i < cnt; i += 256) {
      unsigned gi = gbase + i;
      if (gi < cap) buf[gi] = mbuf[i];
    }
  }

  if (MODE == 1) {
    unsigned sb = ctrl->sel_bin;
    __syncthreads();  // all tile reads done; reuse tiles as match buffer
    __shared__ unsigned bcnt, gbase;
    if (t == 0) bcnt = 0;
    __syncthreads();
    float* mbuf = tiles;
#pragma unroll
    for (int i = 0; i < 8; ++i)
#pragma unroll
      for (int j = 0; j < 8; ++j) {
        float d = acc[i][j];
        int b = (int)(d * BINMUL);
        b = min(max(b, 0), NBINS - 1);
        if ((unsigned)b == sb) {
          unsigned idx = atomicAdd(&bcnt, 1u);
          if (idx < MBUF_CAP) mbuf[idx] = d;
        }
      }
    __syncthreads();
    unsigned cnt = min(bcnt, MBUF_CAP);
    if (t == 0) gbase = atomicAdd(&ctrl->gcount, cnt);
    __syncthreads();
    for (unsigned i = t; i < cnt; i += 256) {
      unsigned gi = gbase + i;
      if (gi < cap) buf[gi] = mbuf[i];
    }
  }

  if (MODE == 2) {
    float s = 0.f;  // per-thread f32 partial
    if (ctrl->use_pow) {
      float c2 = ctrl->c2;
#pragma unroll
      for (int i = 0; i < 8; ++i)
#pragma unroll
        for (int j = 0; j < 8; ++j) {
          float u = fast_exp2(acc[i][j] * c2);  // exp(d*base*0.5)
          float u2 = u * u, u4 = u2 * u2, u8 = u4 * u4, u16 = u8 * u8;
          s += ((u + u2) + (u4 + u8)) + u16;
        }
    } else {
      float sc[KK];
#pragma unroll
      for (int k = 0; k < KK; ++k) sc[k] = ctrl->scales[k];
#pragma unroll
      for (int i = 0; i < 8; ++i)
#pragma unroll
        for (int j = 0; j < 8; ++j) {
          float e = 0.f;
#pragma unroll
          for (int k = 0; k < KK; ++k) e += expf(acc[i][j] * sc[k]);
          s += e;
        }
    }
    // diagonal handled analytically in finalize (exp(0)*KK per diag element)
    double sd = (double)s;
#pragma unroll
    for (int off = 32; off > 0; off >>= 1) sd += __shfl_down(sd, off);
    __shared__ double wsum[4];
    if ((t & 63) == 0) wsum[t >> 6] = sd;
    __syncthreads();
    if (t == 0) atomicAdd(&S[sel], (wsum[0] + wsum[1]) + (wsum[2] + wsum[3]));
  }
}

// ---------------- find coarse bin of rank RMED (parallel scan) ----------------
__global__ void __launch_bounds__(256)
select_bin_kernel(const unsigned* __restrict__ hist, Ctrl* __restrict__ ctrl,
                  int lobin, int hibin, unsigned cap) {
  __shared__ unsigned ps[256];
  __shared__ unsigned s_cumlo;
  int t = threadIdx.x;
  unsigned loc[NBINS / 256];
  unsigned s = 0;
#pragma unroll
  for (int i = 0; i < NBINS / 256; ++i) {
    loc[i] = hist[t * (NBINS / 256) + i];
    s += loc[i];
  }
  ps[t] = s;
  __syncthreads();
  for (int off = 1; off < 256; off <<= 1) {
    unsigned v = ps[t];
    unsigned add = (t >= off) ? ps[t - off] : 0u;
    __syncthreads();
    ps[t] = v + add;
    __syncthreads();
  }
  unsigned incl = ps[t], excl = incl - s;
  if (t == (lobin >> 2)) {  // exclusive cum below bin `lobin`
    unsigned c = excl;
    for (int i = 0; i < (lobin & 3); ++i) c += loc[i];
    s_cumlo = c;
  }
  __syncthreads();
  if (RMED >= excl && RMED < incl) {
    unsigned rank = RMED - excl;
    int bsel = -1;
#pragma unroll
    for (int i = 0; i < NBINS / 256; ++i) {
      if (bsel < 0) {
        if (rank < loc[i]) bsel = t * (NBINS / 256) + i;
        else rank -= loc[i];
      }
    }
    ctrl->sel_bin = (unsigned)bsel;
    ctrl->rank = rank;
    unsigned wrank = RMED - s_cumlo;
    unsigned ok = (bsel >= lobin && bsel < hibin && ctrl->wover == 0u &&
                   ctrl->wcount <= cap && wrank < ctrl->wcount) ? 1u : 0u;
    ctrl->wrank = wrank;
    ctrl->ok = ok;
  }
}

// ---------------- parallel radix select: per-round histogram ----------------
__global__ void __launch_bounds__(256)
radix_hist_kernel(const Ctrl* __restrict__ ctrl, const float* __restrict__ buf,
                  unsigned* __restrict__ gh, int round, unsigned cap) {
  __shared__ unsigned h[256];
  int t = threadIdx.x;
  h[t] = 0;
  __syncthreads();
  unsigned m = min(ctrl->ok ? ctrl->wcount : ctrl->gcount, cap);
  int shift = 24 - 8 * round;
  unsigned pref = ctrl->spref;
  for (unsigned i = blockIdx.x * 256u + t; i < m; i += gridDim.x * 256u) {
    unsigned u = __float_as_uint(buf[i]);
    u ^= (u >> 31) ? 0xFFFFFFFFu : 0x80000000u;
    bool ok = (round == 0) || (((u ^ pref) >> (shift + 8)) == 0u);
    if (ok) atomicAdd(&h[(u >> shift) & 255u], 1u);
  }
  __syncthreads();
  if (h[t]) atomicAdd(&gh[round * 256 + t], h[t]);
}

// ---------------- parallel radix select: per-round bin scan ----------------
__global__ void __launch_bounds__(256)
radix_scan_kernel(Ctrl* __restrict__ ctrl, const unsigned* __restrict__ gh,
                  const float* __restrict__ ksc, int round) {
  __shared__ unsigned ps[256];
  int t = threadIdx.x;
  unsigned rank = (round == 0) ? (ctrl->ok ? ctrl->wrank : ctrl->rank) : ctrl->srank;
  unsigned c = gh[round * 256 + t];
  ps[t] = c;
  __syncthreads();
  for (int off = 1; off < 256; off <<= 1) {
    unsigned v = ps[t];
    unsigned add = (t >= off) ? ps[t - off] : 0u;
    __syncthreads();
    ps[t] = v + add;
    __syncthreads();
  }
  unsigned incl = ps[t], excl = incl - c;
  if (rank >= excl && rank < incl) {
    int shift = 24 - 8 * round;
    unsigned np = ctrl->spref | ((unsigned)t << shift);
    ctrl->spref = np;
    ctrl->srank = rank - excl;
    if (round == 3) {
      unsigned u = (np & 0x80000000u) ? (np ^ 0x80000000u) : ~np;
      float med = __uint_as_float(u);
      ctrl->median = med;
      float base = -1.0f / med;
#pragma unroll
      for (int k = 0; k < KK; ++k) ctrl->scales[k] = base * ksc[k];
      ctrl->c2 = base * 0.5f * 1.44269504088896f;
      ctrl->use_pow = (ksc[0] == 0.5f && ksc[1] == 1.0f && ksc[2] == 2.0f &&
                       ksc[3] == 4.0f && ksc[4] == 8.0f) ? 1u : 0u;
    }
  }
}

// ---------------- finalize ----------------
__global__ void finalize_kernel(const double* __restrict__ S, float* __restrict__ out) {
  if (threadIdx.x == 0 && blockIdx.x == 0) {
    double offd = 1.0 / ((double)NN * (double)(NN - 1));
    double invK = 1.0 / (double)KK;
    double kxx = (S[0] * invK) - (double)NN;  // subtract diagonal (exp(0)=1, KK terms)
    double kyy = (S[1] * invK) - (double)NN;
    double kzz = S[2] * invK;
    double val = offd * (kxx + kyy) - 2.0 * kzz / ((double)NN * (double)NN);
    out[0] = (float)val;
  }
}

extern "C" void kernel_launch(void* const* d_in, const int* in_sizes, int n_in,
                              void* d_out, int out_size, void* d_ws, size_t ws_size,
                              hipStream_t stream) {
  const float* x = (const float*)d_in[0];
  const float* y = (const float*)d_in[1];
  const float* ksc = (const float*)d_in[2];

  char* ws = (char*)d_ws;
  double* S = (double*)ws;                      // 3 doubles          @ 0
  unsigned* hist = (unsigned*)(ws + 64);        // 1024 u32           @ 64
  unsigned* gh = (unsigned*)(ws + 4160);        // 4*256 u32          @ 4160
  Ctrl* ctrl = (Ctrl*)(ws + 8256);              // ~80B               @ 8256
  float* xn = (float*)(ws + 8384);              // 4096 f32
  float* yn = xn + NN;                          // 4096 f32 (ends @ 41152)
  float* buf = (float*)(ws + 65536);            // candidate buffer   @ 64K

  // window tier: wide if scratch allows ~32MB of candidates, else narrow
  size_t avail = (ws_size > 65536) ? (ws_size - 65536) / 4 : 0;
  unsigned cap = (unsigned)((avail < (size_t)(8u << 20)) ? avail : (size_t)(8u << 20));
  int lobin, hibin;
  if (cap >= (4u << 20)) { lobin = 244; hibin = 264; }  // d in [122, 132)
  else                   { lobin = 250; hibin = 256; }  // d in [125, 128)

  hipMemsetAsync(ws, 0, 8384, stream);  // S, hist, gh, ctrl

  norms_kernel<<<32, 256, 0, stream>>>(x, y, xn, yn);
  pair_kernel<0><<<dim3(32, 32), 256, 0, stream>>>(x, y, xn, yn, hist, ctrl, buf, S,
                                                   lobin, hibin, cap);
  select_bin_kernel<<<1, 256, 0, stream>>>(hist, ctrl, lobin, hibin, cap);
  pair_kernel<1><<<dim3(32, 32), 256, 0, stream>>>(x, y, xn, yn, hist, ctrl, buf, S,
                                                   lobin, hibin, cap);
  for (int r = 0; r < 4; ++r) {
    radix_hist_kernel<<<192, 256, 0, stream>>>(ctrl, buf, gh, r, cap);
    radix_scan_kernel<<<1, 256, 0, stream>>>(ctrl, gh, ksc, r);
  }
  pair_kernel<2><<<dim3(32, 32, 3), 256, 0, stream>>>(x, y, xn, yn, hist, ctrl, buf, S,
                                                      lobin, hibin, cap);
  finalize_kernel<<<1, 64, 0, stream>>>(S, (float*)d_out);
}

// Round 8
// 198.263 us; speedup vs baseline: 1.3646x; 1.3646x over previous
//
#include <hip/hip_runtime.h>

#define NN 4096
#define DD 64
#define KK 5
#define NBINS 1024
#define BINMUL 2.0f    // coarse bin width 0.5 over [0, 512)
#define RMED 8388607u  // (NN*NN - 1) / 2
#define MBUF_CAP 8192u // per-block LDS gather capacity (reuses tiles)

typedef short short8 __attribute__((ext_vector_type(8)));
typedef float f32x4 __attribute__((ext_vector_type(4)));

struct Ctrl {
  unsigned wcount;   // window-gathered candidate count (MODE 0)
  unsigned wover;    // 1 if any block overflowed its LDS gather buffer
  unsigned gcount;   // fallback-gathered candidate count (MODE 1)
  unsigned sel_bin;  // selected coarse bin
  unsigned rank;     // rank (0-based) within selected bin (fallback path)
  unsigned ok;       // 1 = window path valid (skip MODE 1)
  unsigned wrank;    // rank within window candidates (window path)
  unsigned spref;    // radix-select prefix (built over 4 rounds)
  unsigned srank;    // remaining rank within prefix
  unsigned use_pow;  // 1 if kernel_scales == [0.5,1,2,4,8]
  float median;
  float c2;          // base*0.5*log2(e)
  float scales[KK];  // base*kernel_scales[k] (general fallback)
};

__device__ inline float fast_exp2(float x) {
  float r;
  asm("v_exp_f32 %0, %1" : "=v"(r) : "v"(x));
  return r;
}
__device__ inline unsigned short bf16_rn(float f) {
  unsigned u = __float_as_uint(f);
  return (unsigned short)((u + 0x7FFFu + ((u >> 16) & 1u)) >> 16);
}
__device__ inline float bf16_val(unsigned short h) {
  return __uint_as_float(((unsigned)h) << 16);
}

// ---------------- split f32 -> bf16 hi/lo ----------------
__global__ void __launch_bounds__(256)
split_kernel(const float* __restrict__ x, const float* __restrict__ y,
             short* __restrict__ xhi, short* __restrict__ xlo,
             short* __restrict__ yhi, short* __restrict__ ylo) {
  unsigned tid = blockIdx.x * 256u + threadIdx.x;  // 0..131071
  unsigned e = tid * 4u;                           // element base
  const float* src;
  short *dhi, *dlo;
  unsigned local;
  if (e < (unsigned)(NN * DD)) { src = x; dhi = xhi; dlo = xlo; local = e; }
  else { src = y; dhi = yhi; dlo = ylo; local = e - NN * DD; }
  float4 v = *(const float4*)(src + local);
  unsigned short h0 = bf16_rn(v.x), h1 = bf16_rn(v.y), h2 = bf16_rn(v.z), h3 = bf16_rn(v.w);
  unsigned short l0 = bf16_rn(v.x - bf16_val(h0));
  unsigned short l1 = bf16_rn(v.y - bf16_val(h1));
  unsigned short l2 = bf16_rn(v.z - bf16_val(h2));
  unsigned short l3 = bf16_rn(v.w - bf16_val(h3));
  unsigned long long H = (unsigned long long)h0 | ((unsigned long long)h1 << 16) |
                         ((unsigned long long)h2 << 32) | ((unsigned long long)h3 << 48);
  unsigned long long L = (unsigned long long)l0 | ((unsigned long long)l1 << 16) |
                         ((unsigned long long)l2 << 32) | ((unsigned long long)l3 << 48);
  *(unsigned long long*)((char*)dhi + (size_t)local * 2) = H;
  *(unsigned long long*)((char*)dlo + (size_t)local * 2) = L;
}

// ---------------- norms (exact f32) ----------------
__global__ void norms_kernel(const float* __restrict__ x, const float* __restrict__ y,
                             float* __restrict__ xn, float* __restrict__ yn) {
  int r = blockIdx.x * blockDim.x + threadIdx.x;  // 0..8191
  const float* src = (r < NN) ? x : y;
  float* dst = (r < NN) ? xn : yn;
  int row = r & (NN - 1);
  const float4* p = (const float4*)(src + (size_t)row * DD);
  float s = 0.f;
#pragma unroll
  for (int i = 0; i < DD / 4; ++i) {
    float4 v = p[i];
    s = fmaf(v.x, v.x, s);
    s = fmaf(v.y, v.y, s);
    s = fmaf(v.z, v.z, s);
    s = fmaf(v.w, v.w, s);
  }
  dst[row] = s;
}

// ---------------- MFMA pair-tile kernel ----------------
// 128x128 tile per block, 4 waves of 64x64, bf16x2 split (hihi+hilo+lohi).
// LDS layout per matrix: [row 0..127][kind hi/lo][k 0..63] bf16, row stride 256B,
// byte offset XOR-swizzled with ((row&7)<<4)  (guide G4).
// MODE 0: coarse hist + window gather (stores d-100)
// MODE 1: fallback gather of sel_bin (stores d-100); early-exit if ctrl->ok
// MODE 2: kernel sums (z=0: xx, z=1: yy, z=2: zz)
template <int MODE>
__global__ void __launch_bounds__(256)
pair_kernel(const short* __restrict__ xhi, const short* __restrict__ xlo,
            const short* __restrict__ yhi, const short* __restrict__ ylo,
            const float* __restrict__ xn, const float* __restrict__ yn,
            unsigned* __restrict__ hist, Ctrl* __restrict__ ctrl,
            float* __restrict__ buf, double* __restrict__ S,
            int lobin, int hibin, unsigned cap) {
  if (MODE == 1) {
    if (ctrl->ok) return;  // window path succeeded
  }
  __shared__ __align__(16) char smem[65536];
  char* As = smem;
  char* Bs = smem + 32768;

  int t = threadIdx.x;
  int sel = (MODE == 2) ? blockIdx.z : 0;
  const short* Ah = (sel == 1) ? yhi : xhi;
  const short* Al = (sel == 1) ? ylo : xlo;
  const short* Bh = (sel == 0) ? xhi : yhi;
  const short* Bl = (sel == 0) ? xlo : ylo;
  const float* An = (sel == 1) ? yn : xn;
  const float* Bn = (sel == 0) ? xn : yn;

  int rowBase = blockIdx.y * 128;
  int colBase = blockIdx.x * 128;

  int lane = t & 63, wid = t >> 6;
  int wr = (wid >> 1) * 64, wc = (wid & 1) * 64;
  int lrow = lane & 15;
  int lk8 = (lane >> 4) * 8;
  int lswz = (lane & 7) << 4;

  // ---- stage 4x16KB tiles (coalesced 16B chunks, swizzled LDS writes) ----
  {
    const char* gAh = (const char*)Ah + (size_t)rowBase * 128;
    const char* gAl = (const char*)Al + (size_t)rowBase * 128;
    const char* gBh = (const char*)Bh + (size_t)colBase * 128;
    const char* gBl = (const char*)Bl + (size_t)colBase * 128;
    short8 rAh[4], rAl[4], rBh[4], rBl[4];
#pragma unroll
    for (int i = 0; i < 4; ++i) {
      int o = t * 16 + i * 4096;
      rAh[i] = *(const short8*)(gAh + o);
      rAl[i] = *(const short8*)(gAl + o);
      rBh[i] = *(const short8*)(gBh + o);
      rBl[i] = *(const short8*)(gBl + o);
    }
#pragma unroll
    for (int i = 0; i < 4; ++i) {
      int o = t * 16 + i * 4096;
      int rr = o >> 7;
      int cc = (o >> 4) & 7;
      int db = (rr * 256 + cc * 16) ^ ((rr & 7) << 4);
      *(short8*)(As + db) = rAh[i];
      *(short8*)(As + db + 128) = rAl[i];
      *(short8*)(Bs + db) = rBh[i];
      *(short8*)(Bs + db + 128) = rBl[i];
    }
  }
  __syncthreads();

  // ---- MFMA compute: acc += Ahi*Bhi + Ahi*Blo + Alo*Bhi ----
  f32x4 acc[4][4] = {};
#pragma unroll
  for (int kc = 0; kc < 2; ++kc) {
    short8 ah[4], al[4], bh[4], bl[4];
#pragma unroll
    for (int m = 0; m < 4; ++m) {
      int by = ((wr + m * 16 + lrow) * 256 + (lk8 + kc * 32) * 2) ^ lswz;
      ah[m] = *(const short8*)(As + by);
      al[m] = *(const short8*)(As + by + 128);
    }
#pragma unroll
    for (int n = 0; n < 4; ++n) {
      int by = ((wc + n * 16 + lrow) * 256 + (lk8 + kc * 32) * 2) ^ lswz;
      bh[n] = *(const short8*)(Bs + by);
      bl[n] = *(const short8*)(Bs + by + 128);
    }
#pragma unroll
    for (int m = 0; m < 4; ++m)
#pragma unroll
      for (int n = 0; n < 4; ++n) {
        acc[m][n] = __builtin_amdgcn_mfma_f32_16x16x32_bf16(ah[m], bh[n], acc[m][n], 0, 0, 0);
        acc[m][n] = __builtin_amdgcn_mfma_f32_16x16x32_bf16(ah[m], bl[n], acc[m][n], 0, 0, 0);
        acc[m][n] = __builtin_amdgcn_mfma_f32_16x16x32_bf16(al[m], bh[n], acc[m][n], 0, 0, 0);
      }
  }

  // C/D map (guide m89): col = lane&15, row = (lane>>4)*4 + reg
  float anv[16], bnv[4];
#pragma unroll
  for (int m = 0; m < 4; ++m)
#pragma unroll
    for (int r = 0; r < 4; ++r)
      anv[m * 4 + r] = An[rowBase + wr + m * 16 + (lane >> 4) * 4 + r];
#pragma unroll
  for (int n = 0; n < 4; ++n) bnv[n] = Bn[colBase + wc + n * 16 + lrow];

  __syncthreads();  // all LDS fragment reads complete; smem reusable

  if (MODE == 0 || MODE == 1) {
    unsigned* h = (unsigned*)Bs;   // 4KB hist (MODE 0)
    float* mbuf = (float*)As;      // 8192-float gather buffer
    __shared__ unsigned bcnt, gbase;
    if (MODE == 0)
      for (int i = t; i < NBINS; i += 256) h[i] = 0;
    if (t == 0) bcnt = 0;
    __syncthreads();
    unsigned sb = (MODE == 1) ? ctrl->sel_bin : 0u;
#pragma unroll
    for (int m = 0; m < 4; ++m)
#pragma unroll
      for (int n = 0; n < 4; ++n)
#pragma unroll
        for (int r = 0; r < 4; ++r) {
          float d = (anv[m * 4 + r] + bnv[n]) - 2.0f * acc[m][n][r];
          int b = (int)(d * BINMUL);
          b = min(max(b, 0), NBINS - 1);
          if (MODE == 0) {
            atomicAdd(&h[b], 1u);
            if (b >= lobin && b < hibin) {
              unsigned idx = atomicAdd(&bcnt, 1u);
              if (idx < MBUF_CAP) mbuf[idx] = d - 100.0f;  // exact for d>=100
              else ctrl->wover = 1u;
            }
          } else {
            if ((unsigned)b == sb) {
              unsigned idx = atomicAdd(&bcnt, 1u);
              if (idx < MBUF_CAP) mbuf[idx] = d - 100.0f;
            }
          }
        }
    __syncthreads();
    if (MODE == 0)
      for (int i = t; i < NBINS; i += 256)
        if (h[i]) atomicAdd(&hist[i], h[i]);
    unsigned cnt = min(bcnt, MBUF_CAP);
    if (t == 0) gbase = atomicAdd(MODE == 0 ? &ctrl->wcount : &ctrl->gcount, cnt);
    __syncthreads();
    for (unsigned i = t; i < cnt; i += 256) {
      unsigned gi = gbase + i;
      if (gi < cap) buf[gi] = mbuf[i];
    }
  }

  if (MODE == 2) {
    float s = 0.f;
    if (ctrl->use_pow) {
      float c2 = ctrl->c2;
#pragma unroll
      for (int m = 0; m < 4; ++m)
#pragma unroll
        for (int n = 0; n < 4; ++n)
#pragma unroll
          for (int r = 0; r < 4; ++r) {
            float d = (anv[m * 4 + r] + bnv[n]) - 2.0f * acc[m][n][r];
            float u = fast_exp2(d * c2);
            float u2 = u * u, u4 = u2 * u2, u8 = u4 * u4, u16 = u8 * u8;
            s += ((u + u2) + (u4 + u8)) + u16;
          }
    } else {
      float sc[KK];
#pragma unroll
      for (int k = 0; k < KK; ++k) sc[k] = ctrl->scales[k];
#pragma unroll
      for (int m = 0; m < 4; ++m)
#pragma unroll
        for (int n = 0; n < 4; ++n)
#pragma unroll
          for (int r = 0; r < 4; ++r) {
            float d = (anv[m * 4 + r] + bnv[n]) - 2.0f * acc[m][n][r];
            float e = 0.f;
#pragma unroll
            for (int k = 0; k < KK; ++k) e += expf(d * sc[k]);
            s += e;
          }
    }
    // diagonal handled analytically in finalize
    double sd = (double)s;
#pragma unroll
    for (int off = 32; off > 0; off >>= 1) sd += __shfl_down(sd, off);
    double* wsum = (double*)As;
    if ((t & 63) == 0) wsum[wid] = sd;
    __syncthreads();
    if (t == 0) atomicAdd(&S[sel], (wsum[0] + wsum[1]) + (wsum[2] + wsum[3]));
  }
}

// ---------------- find coarse bin of rank RMED (parallel scan) ----------------
__global__ void __launch_bounds__(256)
select_bin_kernel(const unsigned* __restrict__ hist, Ctrl* __restrict__ ctrl,
                  int lobin, int hibin, unsigned cap) {
  __shared__ unsigned ps[256];
  __shared__ unsigned s_cumlo;
  int t = threadIdx.x;
  unsigned loc[NBINS / 256];
  unsigned s = 0;
#pragma unroll
  for (int i = 0; i < NBINS / 256; ++i) {
    loc[i] = hist[t * (NBINS / 256) + i];
    s += loc[i];
  }
  ps[t] = s;
  __syncthreads();
  for (int off = 1; off < 256; off <<= 1) {
    unsigned v = ps[t];
    unsigned add = (t >= off) ? ps[t - off] : 0u;
    __syncthreads();
    ps[t] = v + add;
    __syncthreads();
  }
  unsigned incl = ps[t], excl = incl - s;
  if (t == (lobin >> 2)) {  // exclusive cum below bin `lobin`
    unsigned c = excl;
    for (int i = 0; i < (lobin & 3); ++i) c += loc[i];
    s_cumlo = c;
  }
  __syncthreads();
  if (RMED >= excl && RMED < incl) {
    unsigned rank = RMED - excl;
    int bsel = -1;
#pragma unroll
    for (int i = 0; i < NBINS / 256; ++i) {
      if (bsel < 0) {
        if (rank < loc[i]) bsel = t * (NBINS / 256) + i;
        else rank -= loc[i];
      }
    }
    ctrl->sel_bin = (unsigned)bsel;
    ctrl->rank = rank;
    unsigned wrank = RMED - s_cumlo;
    unsigned ok = (bsel >= lobin && bsel < hibin && ctrl->wover == 0u &&
                   ctrl->wcount <= cap && wrank < ctrl->wcount) ? 1u : 0u;
    ctrl->wrank = wrank;
    ctrl->ok = ok;
  }
}

// ---------------- parallel radix select over buf (values are d-100) ----------
__global__ void __launch_bounds__(256)
radix_hist_kernel(const Ctrl* __restrict__ ctrl, const float* __restrict__ buf,
                  unsigned* __restrict__ gh, int round, unsigned cap) {
  __shared__ unsigned h[256];
  int t = threadIdx.x;
  h[t] = 0;
  __syncthreads();
  unsigned m = min(ctrl->ok ? ctrl->wcount : ctrl->gcount, cap);
  int shift = 24 - 8 * round;
  unsigned pref = ctrl->spref;
  for (unsigned i = blockIdx.x * 256u + t; i < m; i += gridDim.x * 256u) {
    unsigned u = __float_as_uint(buf[i]);
    u ^= (u >> 31) ? 0xFFFFFFFFu : 0x80000000u;
    bool ok = (round == 0) || (((u ^ pref) >> (shift + 8)) == 0u);
    if (ok) atomicAdd(&h[(u >> shift) & 255u], 1u);
  }
  __syncthreads();
  if (h[t]) atomicAdd(&gh[round * 256 + t], h[t]);
}

__global__ void __launch_bounds__(256)
radix_scan_kernel(Ctrl* __restrict__ ctrl, const unsigned* __restrict__ gh,
                  const float* __restrict__ ksc, int round) {
  __shared__ unsigned ps[256];
  int t = threadIdx.x;
  unsigned rank = (round == 0) ? (ctrl->ok ? ctrl->wrank : ctrl->rank) : ctrl->srank;
  unsigned c = gh[round * 256 + t];
  ps[t] = c;
  __syncthreads();
  for (int off = 1; off < 256; off <<= 1) {
    unsigned v = ps[t];
    unsigned add = (t >= off) ? ps[t - off] : 0u;
    __syncthreads();
    ps[t] = v + add;
    __syncthreads();
  }
  unsigned incl = ps[t], excl = incl - c;
  if (rank >= excl && rank < incl) {
    int shift = 24 - 8 * round;
    unsigned np = ctrl->spref | ((unsigned)t << shift);
    ctrl->spref = np;
    ctrl->srank = rank - excl;
    if (round == 3) {
      unsigned u = (np & 0x80000000u) ? (np ^ 0x80000000u) : ~np;
      float med = __uint_as_float(u) + 100.0f;  // undo the d-100 store (exact)
      ctrl->median = med;
      float base = -1.0f / med;
#pragma unroll
      for (int k = 0; k < KK; ++k) ctrl->scales[k] = base * ksc[k];
      ctrl->c2 = base * 0.5f * 1.44269504088896f;
      ctrl->use_pow = (ksc[0] == 0.5f && ksc[1] == 1.0f && ksc[2] == 2.0f &&
                       ksc[3] == 4.0f && ksc[4] == 8.0f) ? 1u : 0u;
    }
  }
}

// ---------------- finalize ----------------
__global__ void finalize_kernel(const double* __restrict__ S, float* __restrict__ out) {
  if (threadIdx.x == 0 && blockIdx.x == 0) {
    double offd = 1.0 / ((double)NN * (double)(NN - 1));
    double invK = 1.0 / (double)KK;
    double kxx = (S[0] * invK) - (double)NN;  // subtract diagonal (exp(0)=1, KK terms)
    double kyy = (S[1] * invK) - (double)NN;
    double kzz = S[2] * invK;
    double val = offd * (kxx + kyy) - 2.0 * kzz / ((double)NN * (double)NN);
    out[0] = (float)val;
  }
}

extern "C" void kernel_launch(void* const* d_in, const int* in_sizes, int n_in,
                              void* d_out, int out_size, void* d_ws, size_t ws_size,
                              hipStream_t stream) {
  const float* x = (const float*)d_in[0];
  const float* y = (const float*)d_in[1];
  const float* ksc = (const float*)d_in[2];

  char* ws = (char*)d_ws;
  double* S = (double*)ws;                      // 3 doubles  @ 0
  unsigned* hist = (unsigned*)(ws + 64);        // 1024 u32   @ 64
  unsigned* gh = (unsigned*)(ws + 4160);        // 4*256 u32  @ 4160
  Ctrl* ctrl = (Ctrl*)(ws + 8256);              // ~80B       @ 8256
  float* xn = (float*)(ws + 8384);              // 4096 f32
  float* yn = xn + NN;                          // 4096 f32 (ends @ 41152)
  const size_t SPL = (size_t)NN * DD * 2;       // 512KB per split array
  short* xhi = (short*)(ws + 65536);
  short* xlo = (short*)(ws + 65536 + SPL);
  short* yhi = (short*)(ws + 65536 + 2 * SPL);
  short* ylo = (short*)(ws + 65536 + 3 * SPL);
  size_t bufoff = 65536 + 4 * SPL;              // @ 2162688
  float* buf = (float*)(ws + bufoff);

  size_t avail = (ws_size > bufoff) ? (ws_size - bufoff) / 4 : 0;
  unsigned cap = (unsigned)((avail < (size_t)(8u << 20)) ? avail : (size_t)(8u << 20));
  // window around estimated median d ~ 127.7 (sd of sample median ~0.007);
  // MODE1 exact fallback covers a miss.
  int lobin, hibin;
  if (cap >= 1400000u)      { lobin = 252; hibin = 259; }  // d in [126.0, 129.5)
  else if (cap >= 900000u)  { lobin = 253; hibin = 258; }  // d in [126.5, 129.0)
  else if (cap >= 600000u)  { lobin = 254; hibin = 257; }  // d in [127.0, 128.5)
  else                      { lobin = 254; hibin = 256; }  // d in [127.0, 128.0)

  hipMemsetAsync(ws, 0, 8384, stream);  // S, hist, gh, ctrl

  split_kernel<<<512, 256, 0, stream>>>(x, y, xhi, xlo, yhi, ylo);
  norms_kernel<<<32, 256, 0, stream>>>(x, y, xn, yn);
  pair_kernel<0><<<dim3(32, 32), 256, 0, stream>>>(xhi, xlo, yhi, ylo, xn, yn,
                                                   hist, ctrl, buf, S, lobin, hibin, cap);
  select_bin_kernel<<<1, 256, 0, stream>>>(hist, ctrl, lobin, hibin, cap);
  pair_kernel<1><<<dim3(32, 32), 256, 0, stream>>>(xhi, xlo, yhi, ylo, xn, yn,
                                                   hist, ctrl, buf, S, lobin, hibin, cap);
  for (int r = 0; r < 4; ++r) {
    radix_hist_kernel<<<192, 256, 0, stream>>>(ctrl, buf, gh, r, cap);
    radix_scan_kernel<<<1, 256, 0, stream>>>(ctrl, gh, ksc, r);
  }
  pair_kernel<2><<<dim3(32, 32, 3), 256, 0, stream>>>(xhi, xlo, yhi, ylo, xn, yn,
                                                      hist, ctrl, buf, S, lobin, hibin, cap);
  finalize_kernel<<<1, 64, 0, stream>>>(S, (float*)d_out);
}